// Round 17
// baseline (316.859 us; speedup 1.0000x reference)
//
#include <hip/hip_runtime.h>
#include <cstddef>

#define NU_ 50000
#define NF_ 25000
#define E_  500000
#define CAPF_ 64
#define CAPU_ 40

typedef __attribute__((ext_vector_type(8))) short short8v;
typedef __attribute__((ext_vector_type(4))) float float4v;
typedef __attribute__((ext_vector_type(4))) ushort ushort4v;

constexpr int LDR = 136;

static __device__ __forceinline__ ushort f2bf(float f) {
    uint u = __float_as_uint(f);
    uint r = (u + 0x7fffu + ((u >> 16) & 1u)) >> 16;   // RNE
    return (ushort)r;
}
static __device__ __forceinline__ float bf2f(ushort u) {
    return __uint_as_float(((uint)u) << 16);
}

// ---------------------------------------------------------------------------
// Fused preprocessing. Sections: (1) XCD-partitioned one-pass bucket fill,
// (2)+(3) f2b converts with NON-TEMPORAL access (keep streams out of L2 so
// bucket lines stay resident and accumulate), (4) transposes, (5) W@a.
// ---------------------------------------------------------------------------
struct PPArgs {
    const int* uf_src; const int* uf_dst;
    const int* fu_src; const int* fu_dst;
    int* deg_f; int* deg_u;
    ushort* buck_f; ushort* buck_u;
    const float* xu; const float* xf;
    ushort* bu; ushort* bfo;
    const float* W[5];  ushort* T[5];      // transpose targets (shift 7,7,7,7,6)
    const float* waW[8]; const float* waA[8];
    float* vall;
};

__global__ __launch_bounds__(256) void preprocess(PPArgs A) {
    const int EB  = (E_ + 255) / 256;      // 1954
    const int FBLK = 8 * EB;               // per edge type (8 partitions)
    const int nbA = NU_ * 32 / 256;        // 6250
    const int nbB = NF_ * 32 / 256;        // 3125
    const int nbC = 4 * 64 + 32;           // 288
    int b = blockIdx.x, t = threadIdx.x;
    if (b < 2 * FBLK) {
        const int *src, *dst; int *deg; ushort* buck; int cap, Nd;
        int cb = b;
        if (cb < FBLK) { src = A.uf_src; dst = A.uf_dst; deg = A.deg_f; buck = A.buck_f; cap = CAPF_; Nd = NF_; }
        else           { src = A.fu_src; dst = A.fu_dst; deg = A.deg_u; buck = A.buck_u; cap = CAPU_; Nd = NU_; cb -= FBLK; }
        int p = cb & 7;            // partition (heuristic XCD affinity)
        int e = (cb >> 3) * 256 + t;
        if (e < E_) {
            int d = dst[e];
            if ((d * 8) / Nd == p) {
                int r = atomicAdd(&deg[d], 1);
                if (r < cap) buck[d * cap + r] = (ushort)src[e];   // overflow guard (P ~ 0)
            }
        }
        return;
    }
    b -= 2 * FBLK;
    if (b < nbA) {
        int i = b * 256 + t;
        float4v v = __builtin_nontemporal_load(((const float4v*)A.xu) + i);
        ushort4v o;
        o.x = f2bf(v.x); o.y = f2bf(v.y); o.z = f2bf(v.z); o.w = f2bf(v.w);
        __builtin_nontemporal_store(o, ((ushort4v*)A.bu) + i);
    } else if (b < nbA + nbB) {
        int i = (b - nbA) * 256 + t;
        float4v v = __builtin_nontemporal_load(((const float4v*)A.xf) + i);
        ushort4v o;
        o.x = f2bf(v.x); o.y = f2bf(v.y); o.z = f2bf(v.z); o.w = f2bf(v.w);
        __builtin_nontemporal_store(o, ((ushort4v*)A.bfo) + i);
    } else if (b < nbA + nbB + nbC) {
        int cb = b - nbA - nbB;
        int m, wb, sh;
        if (cb < 256) { m = cb >> 6; wb = cb & 63; sh = 7; }
        else          { m = 4; wb = cb - 256; sh = 6; }
        int idx = wb * 256 + t;
        int k = idx >> sh, c = idx & ((1 << sh) - 1);
        A.T[m][c * 128 + k] = f2bf(__builtin_nontemporal_load(A.W[m] + idx));
    } else {
        int db = b - nbA - nbB - nbC;          // 0..255
        int row = db * 4 + (t >> 6);           // 0..1023 = m*128+k
        int m = row >> 7, k = row & 127, lane = t & 63;
        float2 w = ((const float2*)(A.waW[m] + k * 128))[lane];
        float2 av = ((const float2*)A.waA[m])[lane];
        float s = w.x * av.x + w.y * av.y;
        #pragma unroll
        for (int o = 32; o; o >>= 1) s += __shfl_xor(s, o);
        if (lane == 0) A.vall[row] = s;
    }
}

// ---------------------------------------------------------------------------
// MFMA 128x128 GEMM tile (bf16 in/out), both node types in one dispatch.
// ---------------------------------------------------------------------------
static __device__ __forceinline__ void gemm_tile(const ushort* __restrict__ Xb,
                                                 const ushort* __restrict__ Wt,
                                                 ushort* __restrict__ C, int N, int row0,
                                                 short* Xs, short* Ws) {
    const int t = threadIdx.x;
    for (int i = t; i < 128 * 16; i += 256) {
        int r = i >> 4, c8 = (i & 15) << 3;
        short8v v = {};
        if (row0 + r < N) v = *(const short8v*)(Xb + (size_t)(row0 + r) * 128 + c8);
        *(short8v*)(&Xs[r * LDR + c8]) = v;
    }
    for (int i = t; i < 128 * 16; i += 256) {
        int r = i >> 4, c8 = (i & 15) << 3;
        *(short8v*)(&Ws[r * LDR + c8]) = *(const short8v*)(Wt + r * 128 + c8);
    }
    __syncthreads();

    const int w = t >> 6, l = t & 63;
    const int m0 = (w & 1) * 64;
    const int n0 = (w >> 1) * 64;
    const int frow = l & 15;
    const int koff = (l >> 4) << 3;

    float4v acc[4][4];
    #pragma unroll
    for (int m = 0; m < 4; ++m)
        #pragma unroll
        for (int n = 0; n < 4; ++n) acc[m][n] = (float4v)0.f;

    #pragma unroll
    for (int ks = 0; ks < 4; ++ks) {
        const int k0 = ks * 32 + koff;
        short8v a[4], b[4];
        #pragma unroll
        for (int m = 0; m < 4; ++m)
            a[m] = *(const short8v*)(&Xs[(m0 + m * 16 + frow) * LDR + k0]);
        #pragma unroll
        for (int n = 0; n < 4; ++n)
            b[n] = *(const short8v*)(&Ws[(n0 + n * 16 + frow) * LDR + k0]);
        #pragma unroll
        for (int m = 0; m < 4; ++m)
            #pragma unroll
            for (int n = 0; n < 4; ++n)
                acc[m][n] = __builtin_amdgcn_mfma_f32_16x16x32_bf16(a[m], b[n], acc[m][n], 0, 0, 0);
    }

    const int crow = (l >> 4) << 2;
    const int ccol = l & 15;
    #pragma unroll
    for (int m = 0; m < 4; ++m) {
        #pragma unroll
        for (int r4 = 0; r4 < 4; ++r4) {
            int grow = row0 + m0 + m * 16 + crow + r4;
            if (grow < N) {
                #pragma unroll
                for (int n = 0; n < 4; ++n)
                    C[(size_t)grow * 128 + n0 + n * 16 + ccol] = f2bf(acc[m][n][r4]);
            }
        }
    }
}

__global__ __launch_bounds__(256) void gemm_both(const ushort* __restrict__ Xu, const ushort* __restrict__ Wtu,
                                                 ushort* __restrict__ Cu,
                                                 const ushort* __restrict__ Xf, const ushort* __restrict__ Wtf,
                                                 ushort* __restrict__ Cf) {
    __shared__ short Xs[128 * LDR];
    __shared__ short Ws[128 * LDR];
    const int GU = (NU_ + 127) / 128;
    if ((int)blockIdx.x < GU)
        gemm_tile(Xu, Wtu, Cu, NU_, blockIdx.x * 128, Xs, Ws);
    else
        gemm_tile(Xf, Wtf, Cf, NF_, (blockIdx.x - GU) * 128, Xs, Ws);
}

// ---------------------------------------------------------------------------
// All 4 attention matvecs in one dispatch (each row read once, 2 dots).
// Zero LDS -> full occupancy (latency-bound section).
// ---------------------------------------------------------------------------
__global__ __launch_bounds__(256) void matvec4(const ushort* __restrict__ bu, const ushort* __restrict__ bfo,
                                               const float* __restrict__ v_asn_u, const float* __restrict__ v_adn_u,
                                               const float* __restrict__ v_adn_f, const float* __restrict__ v_asn_f,
                                               float* __restrict__ asn_u, float* __restrict__ adn_u,
                                               float* __restrict__ adn_f, float* __restrict__ asn_f) {
    int row = blockIdx.x * 4 + (threadIdx.x >> 6);
    int lane = threadIdx.x & 63;
    const ushort* X; const float *va, *vb; float *oa, *ob; int r;
    if (row < NU_) { X = bu; va = v_asn_u; vb = v_adn_u; oa = asn_u; ob = adn_u; r = row; }
    else {
        r = row - NU_;
        if (r >= NF_) return;
        X = bfo; va = v_adn_f; vb = v_asn_f; oa = adn_f; ob = asn_f;
    }
    ushort2 x = ((const ushort2*)(X + (size_t)r * 128))[lane];
    float2 va2 = ((const float2*)va)[lane];
    float2 vb2 = ((const float2*)vb)[lane];
    float fx = bf2f(x.x), fy = bf2f(x.y);
    float s1 = fx * va2.x + fy * va2.y;
    float s2 = fx * vb2.x + fy * vb2.y;
    #pragma unroll
    for (int o = 32; o; o >>= 1) { s1 += __shfl_xor(s1, o); s2 += __shfl_xor(s2, o); }
    if (lane == 0) { oa[r] = s1; ob[r] = s2; }
}

// ---------------------------------------------------------------------------
// Fused GAT softmax+aggregate, ushort buckets; bf16 gather + bf16 out.
// No bias (per-column constants cancel exactly through BatchNorm).
// ---------------------------------------------------------------------------
__global__ __launch_bounds__(256) void gat_agg_both(
        const int* __restrict__ deg_f, const ushort* __restrict__ buck_f,
        const float* __restrict__ asn_u, const float* __restrict__ adn_f,
        const ushort* __restrict__ hs_u, ushort* __restrict__ out_f,
        const int* __restrict__ deg_u, const ushort* __restrict__ buck_u,
        const float* __restrict__ asn_f, const float* __restrict__ adn_u,
        const ushort* __restrict__ hs_f, ushort* __restrict__ out_u) {
    const int NBAF = (NF_ + 3) / 4;
    int blk = blockIdx.x;
    const int* deg; const ushort* buck; const float *asn, *adn; const ushort* hs; ushort* out; int Nd, d, cap;
    if (blk < NBAF) {
        deg = deg_f; buck = buck_f; asn = asn_u; adn = adn_f; hs = hs_u; out = out_f;
        Nd = NF_; cap = CAPF_; d = blk * 4 + (threadIdx.x >> 6);
    } else {
        deg = deg_u; buck = buck_u; asn = asn_f; adn = adn_u; hs = hs_f; out = out_u;
        Nd = NU_; cap = CAPU_; d = (blk - NBAF) * 4 + (threadIdx.x >> 6);
    }
    int lane = threadIdx.x & 63;
    if (d >= Nd) return;
    const int beg = d * cap;
    const int end = beg + min(deg[d], cap);
    const float ad = adn[d];
    const int qw = lane >> 4, l16 = lane & 15;
    float acc[8] = {0.f, 0.f, 0.f, 0.f, 0.f, 0.f, 0.f, 0.f};
    float den = 0.f;
    for (int base = beg; base < end; base += 64) {
        int e = base + lane;
        int s = 0; float ev = 0.f;    // inactive lanes: ev=0, s=0 (row-0 load harmless)
        if (e < end) {
            s = buck[e];
            float v = asn[s] + ad;
            v = v > 0.f ? v : 0.2f * v;
            ev = __expf(v);
        }
        float r = ev;
        #pragma unroll
        for (int o = 32; o; o >>= 1) r += __shfl_xor(r, o);
        den += r;
        int cnt4 = (min(64, end - base) + 3) & ~3;
        for (int j = 0; j < cnt4; j += 8) {
            int jj = j + qw;
            float ev0 = __shfl(ev, jj);
            int   sj0 = __shfl(s, jj);
            short8v h0 = *(const short8v*)(hs + (size_t)sj0 * 128 + l16 * 8);
            if (j + 4 < cnt4) {                  // wave-uniform
                float ev1 = __shfl(ev, jj + 4);
                int   sj1 = __shfl(s, jj + 4);
                short8v h1 = *(const short8v*)(hs + (size_t)sj1 * 128 + l16 * 8);
                #pragma unroll
                for (int k = 0; k < 8; ++k)
                    acc[k] += ev0 * bf2f((ushort)h0[k]) + ev1 * bf2f((ushort)h1[k]);
            } else {
                #pragma unroll
                for (int k = 0; k < 8; ++k)
                    acc[k] += ev0 * bf2f((ushort)h0[k]);
            }
        }
    }
    #pragma unroll
    for (int k = 0; k < 8; ++k) {
        acc[k] += __shfl_xor(acc[k], 16);
        acc[k] += __shfl_xor(acc[k], 32);
    }
    if (qw == 0) {
        float inv = 1.f / (den + 1e-16f);
        short8v o;
        #pragma unroll
        for (int k = 0; k < 8; ++k) o[k] = (short)f2bf(acc[k] * inv);
        *(short8v*)(out + (size_t)d * 128 + l16 * 8) = o;
    }
}

// ---------------------------------------------------------------------------
// BN stats on bf16 inputs, two tensors per launch; ushort8 loads.
// ---------------------------------------------------------------------------
__global__ __launch_bounds__(256) void bn_stats2b(const ushort* __restrict__ x1, float* __restrict__ stat1,
                                                  int N1, int B1,
                                                  const ushort* __restrict__ x2, float* __restrict__ stat2,
                                                  int N2, int B2) {
    const ushort* x; float* stat; int N, b, nb;
    if ((int)blockIdx.x < B1) { x = x1; stat = stat1; N = N1; b = blockIdx.x; nb = B1; }
    else { x = x2; stat = stat2; N = N2; b = blockIdx.x - B1; nb = B2; }
    const int t = threadIdx.x;
    const int rg = t >> 4;
    const int c16 = t & 15;
    float s[8] = {0,0,0,0,0,0,0,0}, q[8] = {0,0,0,0,0,0,0,0};
    for (int r = b * 16 + rg; r < N; r += nb * 16) {
        short8v v = *(const short8v*)(x + (size_t)r * 128 + c16 * 8);
        #pragma unroll
        for (int k = 0; k < 8; ++k) {
            float f = bf2f((ushort)v[k]);
            s[k] += f; q[k] += f * f;
        }
    }
    #pragma unroll
    for (int k = 0; k < 8; ++k) {
        s[k] += __shfl_xor(s[k], 16); q[k] += __shfl_xor(q[k], 16);
        s[k] += __shfl_xor(s[k], 32); q[k] += __shfl_xor(q[k], 32);
    }
    __shared__ float rs[4][128], rq[4][128];
    const int w = t >> 6, l = t & 63;
    if (l < 16) {
        #pragma unroll
        for (int k = 0; k < 8; ++k) {
            rs[w][l * 8 + k] = s[k];
            rq[w][l * 8 + k] = q[k];
        }
    }
    __syncthreads();
    if (t < 128) {
        atomicAdd(&stat[t],       rs[0][t] + rs[1][t] + rs[2][t] + rs[3][t]);
        atomicAdd(&stat[128 + t], rq[0][t] + rq[1][t] + rq[2][t] + rq[3][t]);
    }
}

// ---------------------------------------------------------------------------
// BN apply with inline finalize (scale/shift from raw sums; stats L1-resident).
// ---------------------------------------------------------------------------
static __device__ __forceinline__ void bn_scale_shift(const float* __restrict__ stat,
                                                      const float* __restrict__ g,
                                                      const float* __restrict__ b,
                                                      float invN, int c0,
                                                      float* sc, float* sh) {
    #pragma unroll
    for (int k = 0; k < 8; ++k) {
        int c = c0 + k;
        float mu  = stat[c] * invN;
        float var = stat[128 + c] * invN - mu * mu;
        float s = g[c] * rsqrtf(var + 1e-5f);
        sc[k] = s;
        sh[k] = b[c] - mu * s;
    }
}

__global__ void bn_apply2b(const ushort* __restrict__ x1, const float* __restrict__ stat1,
                           const float* __restrict__ g1, const float* __restrict__ b1, float invN1,
                           float* __restrict__ xo1, ushort* __restrict__ xb1, int N1,
                           const ushort* __restrict__ x2, const float* __restrict__ stat2,
                           const float* __restrict__ g2, const float* __restrict__ b2, float invN2,
                           float* __restrict__ xo2, ushort* __restrict__ xb2, int N2) {
    int i = blockIdx.x * 256 + threadIdx.x;
    const ushort* x; const float *stat, *g, *b; float invN; float* xo; ushort* xb;
    if (i < N1 * 16) { x = x1; stat = stat1; g = g1; b = b1; invN = invN1; xo = xo1; xb = xb1; }
    else {
        i -= N1 * 16;
        if (i >= N2 * 16) return;
        x = x2; stat = stat2; g = g2; b = b2; invN = invN2; xo = xo2; xb = xb2;
    }
    int c16 = i & 15;
    short8v v = *(const short8v*)(x + (size_t)i * 8);
    float sc[8], sh[8];
    bn_scale_shift(stat, g, b, invN, c16 * 8, sc, sh);
    float o[8];
    #pragma unroll
    for (int k = 0; k < 8; ++k) {
        float f = bf2f((ushort)v[k]) * sc[k] + sh[k];
        o[k] = f > 0.f ? f : __expf(f) - 1.f;
    }
    if (xo) {
        *(float4*)(xo + (size_t)i * 8)     = make_float4(o[0], o[1], o[2], o[3]);
        *(float4*)(xo + (size_t)i * 8 + 4) = make_float4(o[4], o[5], o[6], o[7]);
    }
    if (xb) {
        short8v u;
        #pragma unroll
        for (int k = 0; k < 8; ++k) u[k] = (short)f2bf(o[k]);
        *(short8v*)(xb + (size_t)i * 8) = u;
    }
}

// single-tensor variant, optional bf16 out, optional health add (+0.1*s[row])
__global__ void bn_apply1b(const ushort* __restrict__ x, const float* __restrict__ stat,
                           const float* __restrict__ g, const float* __restrict__ b, float invN,
                           float* __restrict__ xo, ushort* __restrict__ xb, int N,
                           const float* __restrict__ health) {
    int i = blockIdx.x * 256 + threadIdx.x;
    if (i >= N * 16) return;
    int c16 = i & 15;
    short8v v = *(const short8v*)(x + (size_t)i * 8);
    float sc[8], sh[8];
    bn_scale_shift(stat, g, b, invN, c16 * 8, sc, sh);
    float hv = health ? 0.1f * health[i >> 4] : 0.f;
    float o[8];
    #pragma unroll
    for (int k = 0; k < 8; ++k) {
        float f = bf2f((ushort)v[k]) * sc[k] + sh[k];
        o[k] = (f > 0.f ? f : __expf(f) - 1.f) + hv;
    }
    if (xo) {
        *(float4*)(xo + (size_t)i * 8)     = make_float4(o[0], o[1], o[2], o[3]);
        *(float4*)(xo + (size_t)i * 8 + 4) = make_float4(o[4], o[5], o[6], o[7]);
    }
    if (xb) {
        short8v u;
        #pragma unroll
        for (int k = 0; k < 8; ++k) u[k] = (short)f2bf(o[k]);
        *(short8v*)(xb + (size_t)i * 8) = u;
    }
}

// ---------------------------------------------------------------------------
// Fused MLP: prefs[u] = tanh( leaky_relu(Xb[u]@hw1 + hb1, 0.01) @ hw2 + hb2 )
// ---------------------------------------------------------------------------
__global__ __launch_bounds__(256) void mlp_mfma(const ushort* __restrict__ Xb,
                                                const ushort* __restrict__ Wt,   // hw1t [64][128]
                                                const float* __restrict__ hb1,
                                                const float* __restrict__ hw2,
                                                const float* __restrict__ hb2,
                                                float* __restrict__ prefs, int N) {
    __shared__ short Xs[128 * LDR];
    __shared__ short Ws[64 * LDR];
    const int t = threadIdx.x;
    const int row0 = blockIdx.x * 128;

    for (int i = t; i < 128 * 16; i += 256) {
        int r = i >> 4, c8 = (i & 15) << 3;
        short8v v = {};
        if (row0 + r < N) v = *(const short8v*)(Xb + (size_t)(row0 + r) * 128 + c8);
        *(short8v*)(&Xs[r * LDR + c8]) = v;
    }
    for (int i = t; i < 64 * 16; i += 256) {
        int r = i >> 4, c8 = (i & 15) << 3;
        *(short8v*)(&Ws[r * LDR + c8]) = *(const short8v*)(Wt + r * 128 + c8);
    }
    __syncthreads();

    const int w = t >> 6, l = t & 63;
    const int m0 = w * 32;
    const int frow = l & 15;
    const int koff = (l >> 4) << 3;

    float4v acc[2][4];
    #pragma unroll
    for (int m = 0; m < 2; ++m)
        #pragma unroll
        for (int n = 0; n < 4; ++n) acc[m][n] = (float4v)0.f;

    #pragma unroll
    for (int ks = 0; ks < 4; ++ks) {
        const int k0 = ks * 32 + koff;
        short8v a[2], b[4];
        #pragma unroll
        for (int m = 0; m < 2; ++m)
            a[m] = *(const short8v*)(&Xs[(m0 + m * 16 + frow) * LDR + k0]);
        #pragma unroll
        for (int n = 0; n < 4; ++n)
            b[n] = *(const short8v*)(&Ws[(n * 16 + frow) * LDR + k0]);
        #pragma unroll
        for (int m = 0; m < 2; ++m)
            #pragma unroll
            for (int n = 0; n < 4; ++n)
                acc[m][n] = __builtin_amdgcn_mfma_f32_16x16x32_bf16(a[m], b[n], acc[m][n], 0, 0, 0);
    }

    float hb1v[4], hw2v[4];
    #pragma unroll
    for (int n = 0; n < 4; ++n) {
        int col = n * 16 + (l & 15);
        hb1v[n] = hb1[col];
        hw2v[n] = hw2[col];
    }
    const float hb2v = hb2[0];
    #pragma unroll
    for (int m = 0; m < 2; ++m) {
        #pragma unroll
        for (int r4 = 0; r4 < 4; ++r4) {
            float p = 0.f;
            #pragma unroll
            for (int n = 0; n < 4; ++n) {
                float v = acc[m][n][r4] + hb1v[n];
                v = v > 0.f ? v : 0.01f * v;
                p += v * hw2v[n];
            }
            p += __shfl_xor(p, 1);
            p += __shfl_xor(p, 2);
            p += __shfl_xor(p, 4);
            p += __shfl_xor(p, 8);
            int grow = row0 + m0 + m * 16 + ((l >> 4) << 2) + r4;
            if ((l & 15) == 0 && grow < N) prefs[grow] = tanhf(p + hb2v);
        }
    }
}

// s[he_food[e]] += prefs[he_user[e]] * score[e]
__global__ void health_scatter(const int* __restrict__ hu, const int* __restrict__ hf,
                               const float* __restrict__ score, const float* __restrict__ prefs,
                               float* __restrict__ s, int E) {
    int e = blockIdx.x * 256 + threadIdx.x;
    if (e >= E) return;
    atomicAdd(&s[hf[e]], prefs[hu[e]] * score[e]);
}

// ---------------------------------------------------------------------------
extern "C" void kernel_launch(void* const* d_in, const int* in_sizes, int n_in,
                              void* d_out, int out_size, void* d_ws, size_t ws_size,
                              hipStream_t stream) {
    const float* x_user = (const float*)d_in[0];
    const float* x_food = (const float*)d_in[1];
    const int* uf_src = (const int*)d_in[2];
    const int* uf_dst = (const int*)d_in[3];
    const int* fu_src = (const int*)d_in[4];
    const int* fu_dst = (const int*)d_in[5];
    const int* he_user = (const int*)d_in[6];
    const int* he_food = (const int*)d_in[7];
    const float* scores = (const float*)d_in[8];
    // GAT biases (d_in[13],[18],[23],[28]) cancel through BatchNorm — unused.
    const float* bn1_user_g = (const float*)d_in[29];
    const float* bn1_user_b = (const float*)d_in[30];
    const float* bn1_food_g = (const float*)d_in[31];
    const float* bn1_food_b = (const float*)d_in[32];
    const float* bn2_user_g = (const float*)d_in[33];
    const float* bn2_user_b = (const float*)d_in[34];
    const float* bn2_food_g = (const float*)d_in[35];
    const float* bn2_food_b = (const float*)d_in[36];
    const float* hw1 = (const float*)d_in[37];
    const float* hb1 = (const float*)d_in[38];
    const float* hw2 = (const float*)d_in[39];
    const float* hb2 = (const float*)d_in[40];

    float* outp  = (float*)d_out;
    float* xu2   = outp;                          // [NU,128]
    float* xf2   = outp + (size_t)NU_ * 128;      // [NF,128]
    float* prefs = xf2 + (size_t)NF_ * 128;       // [NU]

    // ---- workspace layout ----
    float* ws = (float*)d_ws;
    ushort* hs_u = (ushort*)ws;                        // NU*128 bf16
    ushort* hs_f = hs_u + (size_t)NU_ * 128;           // NF*128
    float* base1 = ws + (size_t)(NU_ + NF_) * 64;
    ushort* xu1b = (ushort*)base1;                     // NU*128
    ushort* xf1b = xu1b + (size_t)NU_ * 128;           // NF*128
    float* base2 = base1 + (size_t)(NU_ + NF_) * 64;
    ushort* xu2b = (ushort*)base2;                     // NU*128 (input bf16, then L2 raw out)
    ushort* xf2b = xu2b + (size_t)NU_ * 128;           // NF*128
    float* base3 = base2 + (size_t)(NU_ + NF_) * 64;
    float* asn_u = base3;                              // NU
    float* adn_u = asn_u + NU_;                        // NU
    float* asn_f = adn_u + NU_;                        // NF
    float* adn_f = asn_f + NF_;                        // NF
    // --- zeroed-once region ---
    float* stat4 = adn_f + NF_;                        // 4*256
    float* sbuf  = stat4 + 1024;                       // NF
    int*   deg_f = (int*)(sbuf + NF_);                 // NF
    int*   deg_u = deg_f + NF_;                        // NU
    // --- zeroed-once region end ---
    ushort* buck_f = (ushort*)(deg_u + NU_);           // NF*CAPF ushort
    ushort* buck_u = buck_f + (size_t)NF_ * CAPF_;     // NU*CAPU ushort
    ushort* wt0  = buck_u + (size_t)NU_ * CAPU_;       // 128*128 each
    ushort* wt1  = wt0 + 16384;
    ushort* wt2  = wt1 + 16384;
    ushort* wt3  = wt2 + 16384;
    ushort* hw1t = wt3 + 16384;                        // 64*128
    float* vall  = (float*)(hw1t + 8192);              // 8*128

    const size_t zero_elems = 1024 + NF_ + NF_ + NU_;
    hipMemsetAsync(stat4, 0, zero_elems * sizeof(float), stream);

    // --- fused preprocessing: XCD-partitioned fill first, BW sections backfill ---
    const int EB = (E_ + 255) / 256;
    const int FBLK = 8 * EB;
    PPArgs pp;
    pp.uf_src = uf_src; pp.uf_dst = uf_dst;
    pp.fu_src = fu_src; pp.fu_dst = fu_dst;
    pp.deg_f = deg_f; pp.deg_u = deg_u;
    pp.buck_f = buck_f; pp.buck_u = buck_u;
    pp.xu = x_user; pp.xf = x_food; pp.bu = xu2b; pp.bfo = xf2b;
    pp.W[0] = (const float*)d_in[9];  pp.T[0] = wt0;
    pp.W[1] = (const float*)d_in[14]; pp.T[1] = wt1;
    pp.W[2] = (const float*)d_in[19]; pp.T[2] = wt2;
    pp.W[3] = (const float*)d_in[24]; pp.T[3] = wt3;
    pp.W[4] = hw1;                    pp.T[4] = hw1t;
    pp.waW[0] = (const float*)d_in[9];  pp.waA[0] = (const float*)d_in[11];
    pp.waW[1] = (const float*)d_in[10]; pp.waA[1] = (const float*)d_in[12];
    pp.waW[2] = (const float*)d_in[14]; pp.waA[2] = (const float*)d_in[16];
    pp.waW[3] = (const float*)d_in[15]; pp.waA[3] = (const float*)d_in[17];
    pp.waW[4] = (const float*)d_in[19]; pp.waA[4] = (const float*)d_in[21];
    pp.waW[5] = (const float*)d_in[20]; pp.waA[5] = (const float*)d_in[22];
    pp.waW[6] = (const float*)d_in[24]; pp.waA[6] = (const float*)d_in[26];
    pp.waW[7] = (const float*)d_in[25]; pp.waA[7] = (const float*)d_in[27];
    pp.vall = vall;
    const int PPB = 2 * FBLK + NU_ * 32 / 256 + NF_ * 32 / 256 + 288 + 256;
    preprocess<<<PPB, 256, 0, stream>>>(pp);

    const int GB  = (NU_ + 127) / 128 + (NF_ + 127) / 128;        // 587
    const int MVB = (NU_ + NF_ + 3) / 4;                          // 18750
    const int AGB = (NF_ + 3) / 4 + (NU_ + 3) / 4;                // 18750
    const int APB = ((NU_ + NF_) * 16 + 255) / 256;               // 4688
    const float invNU = 1.0f / NU_, invNF = 1.0f / NF_;

    // ---- layer 1 ----
    gemm_both<<<GB, 256, 0, stream>>>(xu2b, wt0, hs_u, xf2b, wt1, hs_f);
    matvec4<<<MVB, 256, 0, stream>>>(xu2b, xf2b, vall + 0, vall + 384, vall + 128, vall + 256,
                                     asn_u, adn_u, adn_f, asn_f);
    gat_agg_both<<<AGB, 256, 0, stream>>>(deg_f, buck_f, asn_u, adn_f, hs_u, xf1b,
                                          deg_u, buck_u, asn_f, adn_u, hs_f, xu1b);
    bn_stats2b<<<768, 256, 0, stream>>>(xu1b, stat4 + 0, NU_, 512, xf1b, stat4 + 256, NF_, 256);
    bn_apply2b<<<APB, 256, 0, stream>>>(
        xu1b, stat4 + 0,   bn1_user_g, bn1_user_b, invNU, (float*)nullptr, xu1b, NU_,
        xf1b, stat4 + 256, bn1_food_g, bn1_food_b, invNF, (float*)nullptr, xf1b, NF_);

    // ---- layer 2 ----
    gemm_both<<<GB, 256, 0, stream>>>(xu1b, wt2, hs_u, xf1b, wt3, hs_f);
    matvec4<<<MVB, 256, 0, stream>>>(xu1b, xf1b, vall + 512, vall + 896, vall + 640, vall + 768,
                                     asn_u, adn_u, adn_f, asn_f);
    gat_agg_both<<<AGB, 256, 0, stream>>>(deg_f, buck_f, asn_u, adn_f, hs_u, xf2b,
                                          deg_u, buck_u, asn_f, adn_u, hs_f, xu2b);
    bn_stats2b<<<768, 256, 0, stream>>>(xu2b, stat4 + 512, NU_, 512, xf2b, stat4 + 768, NF_, 256);
    // user half: fp32 out + bf16 (for MLP)
    bn_apply1b<<<(NU_ * 16 + 255) / 256, 256, 0, stream>>>(
        xu2b, stat4 + 512, bn2_user_g, bn2_user_b, invNU, xu2, xu2b, NU_, (const float*)nullptr);
    // ---- health preference MLP + scatter ----
    mlp_mfma<<<(NU_ + 127) / 128, 256, 0, stream>>>(xu2b, hw1t, hb1, hw2, hb2, prefs, NU_);
    health_scatter<<<EB, 256, 0, stream>>>(he_user, he_food, scores, prefs, sbuf, E_);
    // food half: fp32 out with fused health add
    bn_apply1b<<<(NF_ * 16 + 255) / 256, 256, 0, stream>>>(
        xf2b, stat4 + 768, bn2_food_g, bn2_food_b, invNF, xf2, (ushort*)nullptr, NF_, sbuf);
}

// Round 18
// 313.040 us; speedup vs baseline: 1.0122x; 1.0122x over previous
//
#include <hip/hip_runtime.h>
#include <cstddef>

#define NU_ 50000
#define NF_ 25000
#define E_  500000
#define CAPF_ 96
#define CAPU_ 48

typedef __attribute__((ext_vector_type(8))) short short8v;
typedef __attribute__((ext_vector_type(4))) float float4v;

constexpr int LDR = 136;

static __device__ __forceinline__ ushort f2bf(float f) {
    uint u = __float_as_uint(f);
    uint r = (u + 0x7fffu + ((u >> 16) & 1u)) >> 16;   // RNE
    return (ushort)r;
}
static __device__ __forceinline__ float bf2f(ushort u) {
    return __uint_as_float(((uint)u) << 16);
}

// ---------------------------------------------------------------------------
// Fused preprocessing. Sections: (1) XCD-partitioned one-pass bucket fill
// (partition p = blockIdx&7 handles dst range p -> writes to a given bucket
// slice come from ~one XCD, so dirty L2 lines accumulate before writeback),
// (2) f2b(x_user), (3) f2b(x_food), (4) weight transposes, (5) W@a vectors.
// ---------------------------------------------------------------------------
struct PPArgs {
    const int* uf_src; const int* uf_dst;
    const int* fu_src; const int* fu_dst;
    int* deg_f; int* deg_u;
    ushort* buck_f; ushort* buck_u;
    const float* xu; const float* xf;
    ushort* bu; ushort* bfo;
    const float* W[5];  ushort* T[5];      // transpose targets (shift 7,7,7,7,6)
    const float* waW[8]; const float* waA[8];
    float* vall;
};

__global__ __launch_bounds__(256) void preprocess(PPArgs A) {
    const int EB  = (E_ + 255) / 256;      // 1954
    const int FBLK = 8 * EB;               // per edge type (8 partitions)
    const int nbA = NU_ * 32 / 256;        // 6250
    const int nbB = NF_ * 32 / 256;        // 3125
    const int nbC = 4 * 64 + 32;           // 288
    int b = blockIdx.x, t = threadIdx.x;
    if (b < 2 * FBLK) {
        const int *src, *dst; int *deg; ushort* buck; int cap, Nd;
        int cb = b;
        if (cb < FBLK) { src = A.uf_src; dst = A.uf_dst; deg = A.deg_f; buck = A.buck_f; cap = CAPF_; Nd = NF_; }
        else           { src = A.fu_src; dst = A.fu_dst; deg = A.deg_u; buck = A.buck_u; cap = CAPU_; Nd = NU_; cb -= FBLK; }
        int p = cb & 7;            // partition (heuristic XCD affinity)
        int e = (cb >> 3) * 256 + t;
        if (e < E_) {
            int d = dst[e];
            if ((d * 8) / Nd == p) {
                int r = atomicAdd(&deg[d], 1);
                if (r < cap) buck[d * cap + r] = (ushort)src[e];   // overflow guard (P ~ 0)
            }
        }
        return;
    }
    b -= 2 * FBLK;
    if (b < nbA) {
        int i = b * 256 + t;
        float4 v = ((const float4*)A.xu)[i];
        ushort4 o; o.x = f2bf(v.x); o.y = f2bf(v.y); o.z = f2bf(v.z); o.w = f2bf(v.w);
        ((ushort4*)A.bu)[i] = o;
    } else if (b < nbA + nbB) {
        int i = (b - nbA) * 256 + t;
        float4 v = ((const float4*)A.xf)[i];
        ushort4 o; o.x = f2bf(v.x); o.y = f2bf(v.y); o.z = f2bf(v.z); o.w = f2bf(v.w);
        ((ushort4*)A.bfo)[i] = o;
    } else if (b < nbA + nbB + nbC) {
        int cb = b - nbA - nbB;
        int m, wb, sh;
        if (cb < 256) { m = cb >> 6; wb = cb & 63; sh = 7; }
        else          { m = 4; wb = cb - 256; sh = 6; }
        int idx = wb * 256 + t;
        int k = idx >> sh, c = idx & ((1 << sh) - 1);
        A.T[m][c * 128 + k] = f2bf(A.W[m][idx]);
    } else {
        int db = b - nbA - nbB - nbC;          // 0..255
        int row = db * 4 + (t >> 6);           // 0..1023 = m*128+k
        int m = row >> 7, k = row & 127, lane = t & 63;
        float2 w = ((const float2*)(A.waW[m] + k * 128))[lane];
        float2 av = ((const float2*)A.waA[m])[lane];
        float s = w.x * av.x + w.y * av.y;
        #pragma unroll
        for (int o = 32; o; o >>= 1) s += __shfl_xor(s, o);
        if (lane == 0) A.vall[row] = s;
    }
}

// ---------------------------------------------------------------------------
// MFMA 128x128 GEMM tile (bf16 in/out), both node types in one dispatch.
// ---------------------------------------------------------------------------
static __device__ __forceinline__ void gemm_tile(const ushort* __restrict__ Xb,
                                                 const ushort* __restrict__ Wt,
                                                 ushort* __restrict__ C, int N, int row0,
                                                 short* Xs, short* Ws) {
    const int t = threadIdx.x;
    for (int i = t; i < 128 * 16; i += 256) {
        int r = i >> 4, c8 = (i & 15) << 3;
        short8v v = {};
        if (row0 + r < N) v = *(const short8v*)(Xb + (size_t)(row0 + r) * 128 + c8);
        *(short8v*)(&Xs[r * LDR + c8]) = v;
    }
    for (int i = t; i < 128 * 16; i += 256) {
        int r = i >> 4, c8 = (i & 15) << 3;
        *(short8v*)(&Ws[r * LDR + c8]) = *(const short8v*)(Wt + r * 128 + c8);
    }
    __syncthreads();

    const int w = t >> 6, l = t & 63;
    const int m0 = (w & 1) * 64;
    const int n0 = (w >> 1) * 64;
    const int frow = l & 15;
    const int koff = (l >> 4) << 3;

    float4v acc[4][4];
    #pragma unroll
    for (int m = 0; m < 4; ++m)
        #pragma unroll
        for (int n = 0; n < 4; ++n) acc[m][n] = (float4v)0.f;

    #pragma unroll
    for (int ks = 0; ks < 4; ++ks) {
        const int k0 = ks * 32 + koff;
        short8v a[4], b[4];
        #pragma unroll
        for (int m = 0; m < 4; ++m)
            a[m] = *(const short8v*)(&Xs[(m0 + m * 16 + frow) * LDR + k0]);
        #pragma unroll
        for (int n = 0; n < 4; ++n)
            b[n] = *(const short8v*)(&Ws[(n0 + n * 16 + frow) * LDR + k0]);
        #pragma unroll
        for (int m = 0; m < 4; ++m)
            #pragma unroll
            for (int n = 0; n < 4; ++n)
                acc[m][n] = __builtin_amdgcn_mfma_f32_16x16x32_bf16(a[m], b[n], acc[m][n], 0, 0, 0);
    }

    const int crow = (l >> 4) << 2;
    const int ccol = l & 15;
    #pragma unroll
    for (int m = 0; m < 4; ++m) {
        #pragma unroll
        for (int r4 = 0; r4 < 4; ++r4) {
            int grow = row0 + m0 + m * 16 + crow + r4;
            if (grow < N) {
                #pragma unroll
                for (int n = 0; n < 4; ++n)
                    C[(size_t)grow * 128 + n0 + n * 16 + ccol] = f2bf(acc[m][n][r4]);
            }
        }
    }
}

__global__ __launch_bounds__(256) void gemm_both(const ushort* __restrict__ Xu, const ushort* __restrict__ Wtu,
                                                 ushort* __restrict__ Cu,
                                                 const ushort* __restrict__ Xf, const ushort* __restrict__ Wtf,
                                                 ushort* __restrict__ Cf) {
    __shared__ short Xs[128 * LDR];
    __shared__ short Ws[128 * LDR];
    const int GU = (NU_ + 127) / 128;
    if ((int)blockIdx.x < GU)
        gemm_tile(Xu, Wtu, Cu, NU_, blockIdx.x * 128, Xs, Ws);
    else
        gemm_tile(Xf, Wtf, Cf, NF_, (blockIdx.x - GU) * 128, Xs, Ws);
}

// ---------------------------------------------------------------------------
// All 4 attention matvecs in one dispatch (each row read once, 2 dots).
// Zero LDS -> full occupancy (latency-bound section).
// ---------------------------------------------------------------------------
__global__ __launch_bounds__(256) void matvec4(const ushort* __restrict__ bu, const ushort* __restrict__ bfo,
                                               const float* __restrict__ v_asn_u, const float* __restrict__ v_adn_u,
                                               const float* __restrict__ v_adn_f, const float* __restrict__ v_asn_f,
                                               float* __restrict__ asn_u, float* __restrict__ adn_u,
                                               float* __restrict__ adn_f, float* __restrict__ asn_f) {
    int row = blockIdx.x * 4 + (threadIdx.x >> 6);
    int lane = threadIdx.x & 63;
    const ushort* X; const float *va, *vb; float *oa, *ob; int r;
    if (row < NU_) { X = bu; va = v_asn_u; vb = v_adn_u; oa = asn_u; ob = adn_u; r = row; }
    else {
        r = row - NU_;
        if (r >= NF_) return;
        X = bfo; va = v_adn_f; vb = v_asn_f; oa = adn_f; ob = asn_f;
    }
    ushort2 x = ((const ushort2*)(X + (size_t)r * 128))[lane];
    float2 va2 = ((const float2*)va)[lane];
    float2 vb2 = ((const float2*)vb)[lane];
    float fx = bf2f(x.x), fy = bf2f(x.y);
    float s1 = fx * va2.x + fy * va2.y;
    float s2 = fx * vb2.x + fy * vb2.y;
    #pragma unroll
    for (int o = 32; o; o >>= 1) { s1 += __shfl_xor(s1, o); s2 += __shfl_xor(s2, o); }
    if (lane == 0) { oa[r] = s1; ob[r] = s2; }
}

// ---------------------------------------------------------------------------
// Fused GAT softmax+aggregate, ushort buckets; bf16 gather + bf16 out.
// No bias (per-column constants cancel exactly through BatchNorm).
// ---------------------------------------------------------------------------
__global__ __launch_bounds__(256) void gat_agg_both(
        const int* __restrict__ deg_f, const ushort* __restrict__ buck_f,
        const float* __restrict__ asn_u, const float* __restrict__ adn_f,
        const ushort* __restrict__ hs_u, ushort* __restrict__ out_f,
        const int* __restrict__ deg_u, const ushort* __restrict__ buck_u,
        const float* __restrict__ asn_f, const float* __restrict__ adn_u,
        const ushort* __restrict__ hs_f, ushort* __restrict__ out_u) {
    const int NBAF = (NF_ + 3) / 4;
    int blk = blockIdx.x;
    const int* deg; const ushort* buck; const float *asn, *adn; const ushort* hs; ushort* out; int Nd, d, cap;
    if (blk < NBAF) {
        deg = deg_f; buck = buck_f; asn = asn_u; adn = adn_f; hs = hs_u; out = out_f;
        Nd = NF_; cap = CAPF_; d = blk * 4 + (threadIdx.x >> 6);
    } else {
        deg = deg_u; buck = buck_u; asn = asn_f; adn = adn_u; hs = hs_f; out = out_u;
        Nd = NU_; cap = CAPU_; d = (blk - NBAF) * 4 + (threadIdx.x >> 6);
    }
    int lane = threadIdx.x & 63;
    if (d >= Nd) return;
    const int beg = d * cap;
    const int end = beg + min(deg[d], cap);
    const float ad = adn[d];
    const int qw = lane >> 4, l16 = lane & 15;
    float acc[8] = {0.f, 0.f, 0.f, 0.f, 0.f, 0.f, 0.f, 0.f};
    float den = 0.f;
    for (int base = beg; base < end; base += 64) {
        int e = base + lane;
        int s = 0; float ev = 0.f;    // inactive lanes: ev=0, s=0 (row-0 load harmless)
        if (e < end) {
            s = buck[e];
            float v = asn[s] + ad;
            v = v > 0.f ? v : 0.2f * v;
            ev = __expf(v);
        }
        float r = ev;
        #pragma unroll
        for (int o = 32; o; o >>= 1) r += __shfl_xor(r, o);
        den += r;
        int cnt4 = (min(64, end - base) + 3) & ~3;
        for (int j = 0; j < cnt4; j += 8) {
            int jj = j + qw;
            float ev0 = __shfl(ev, jj);
            int   sj0 = __shfl(s, jj);
            short8v h0 = *(const short8v*)(hs + (size_t)sj0 * 128 + l16 * 8);
            if (j + 4 < cnt4) {                  // wave-uniform
                float ev1 = __shfl(ev, jj + 4);
                int   sj1 = __shfl(s, jj + 4);
                short8v h1 = *(const short8v*)(hs + (size_t)sj1 * 128 + l16 * 8);
                #pragma unroll
                for (int k = 0; k < 8; ++k)
                    acc[k] += ev0 * bf2f((ushort)h0[k]) + ev1 * bf2f((ushort)h1[k]);
            } else {
                #pragma unroll
                for (int k = 0; k < 8; ++k)
                    acc[k] += ev0 * bf2f((ushort)h0[k]);
            }
        }
    }
    #pragma unroll
    for (int k = 0; k < 8; ++k) {
        acc[k] += __shfl_xor(acc[k], 16);
        acc[k] += __shfl_xor(acc[k], 32);
    }
    if (qw == 0) {
        float inv = 1.f / (den + 1e-16f);
        short8v o;
        #pragma unroll
        for (int k = 0; k < 8; ++k) o[k] = (short)f2bf(acc[k] * inv);
        *(short8v*)(out + (size_t)d * 128 + l16 * 8) = o;
    }
}

// ---------------------------------------------------------------------------
// BN stats on bf16 inputs, two tensors per launch; ushort8 loads.
// ---------------------------------------------------------------------------
__global__ __launch_bounds__(256) void bn_stats2b(const ushort* __restrict__ x1, float* __restrict__ stat1,
                                                  int N1, int B1,
                                                  const ushort* __restrict__ x2, float* __restrict__ stat2,
                                                  int N2, int B2) {
    const ushort* x; float* stat; int N, b, nb;
    if ((int)blockIdx.x < B1) { x = x1; stat = stat1; N = N1; b = blockIdx.x; nb = B1; }
    else { x = x2; stat = stat2; N = N2; b = blockIdx.x - B1; nb = B2; }
    const int t = threadIdx.x;
    const int rg = t >> 4;
    const int c16 = t & 15;
    float s[8] = {0,0,0,0,0,0,0,0}, q[8] = {0,0,0,0,0,0,0,0};
    for (int r = b * 16 + rg; r < N; r += nb * 16) {
        short8v v = *(const short8v*)(x + (size_t)r * 128 + c16 * 8);
        #pragma unroll
        for (int k = 0; k < 8; ++k) {
            float f = bf2f((ushort)v[k]);
            s[k] += f; q[k] += f * f;
        }
    }
    #pragma unroll
    for (int k = 0; k < 8; ++k) {
        s[k] += __shfl_xor(s[k], 16); q[k] += __shfl_xor(q[k], 16);
        s[k] += __shfl_xor(s[k], 32); q[k] += __shfl_xor(q[k], 32);
    }
    __shared__ float rs[4][128], rq[4][128];
    const int w = t >> 6, l = t & 63;
    if (l < 16) {
        #pragma unroll
        for (int k = 0; k < 8; ++k) {
            rs[w][l * 8 + k] = s[k];
            rq[w][l * 8 + k] = q[k];
        }
    }
    __syncthreads();
    if (t < 128) {
        atomicAdd(&stat[t],       rs[0][t] + rs[1][t] + rs[2][t] + rs[3][t]);
        atomicAdd(&stat[128 + t], rq[0][t] + rq[1][t] + rq[2][t] + rq[3][t]);
    }
}

// ---------------------------------------------------------------------------
// BN apply with inline finalize (scale/shift from raw sums; stats L1-resident).
// ---------------------------------------------------------------------------
static __device__ __forceinline__ void bn_scale_shift(const float* __restrict__ stat,
                                                      const float* __restrict__ g,
                                                      const float* __restrict__ b,
                                                      float invN, int c0,
                                                      float* sc, float* sh) {
    #pragma unroll
    for (int k = 0; k < 8; ++k) {
        int c = c0 + k;
        float mu  = stat[c] * invN;
        float var = stat[128 + c] * invN - mu * mu;
        float s = g[c] * rsqrtf(var + 1e-5f);
        sc[k] = s;
        sh[k] = b[c] - mu * s;
    }
}

__global__ void bn_apply2b(const ushort* __restrict__ x1, const float* __restrict__ stat1,
                           const float* __restrict__ g1, const float* __restrict__ b1, float invN1,
                           float* __restrict__ xo1, ushort* __restrict__ xb1, int N1,
                           const ushort* __restrict__ x2, const float* __restrict__ stat2,
                           const float* __restrict__ g2, const float* __restrict__ b2, float invN2,
                           float* __restrict__ xo2, ushort* __restrict__ xb2, int N2) {
    int i = blockIdx.x * 256 + threadIdx.x;
    const ushort* x; const float *stat, *g, *b; float invN; float* xo; ushort* xb;
    if (i < N1 * 16) { x = x1; stat = stat1; g = g1; b = b1; invN = invN1; xo = xo1; xb = xb1; }
    else {
        i -= N1 * 16;
        if (i >= N2 * 16) return;
        x = x2; stat = stat2; g = g2; b = b2; invN = invN2; xo = xo2; xb = xb2;
    }
    int c16 = i & 15;
    short8v v = *(const short8v*)(x + (size_t)i * 8);
    float sc[8], sh[8];
    bn_scale_shift(stat, g, b, invN, c16 * 8, sc, sh);
    float o[8];
    #pragma unroll
    for (int k = 0; k < 8; ++k) {
        float f = bf2f((ushort)v[k]) * sc[k] + sh[k];
        o[k] = f > 0.f ? f : __expf(f) - 1.f;
    }
    if (xo) {
        *(float4*)(xo + (size_t)i * 8)     = make_float4(o[0], o[1], o[2], o[3]);
        *(float4*)(xo + (size_t)i * 8 + 4) = make_float4(o[4], o[5], o[6], o[7]);
    }
    if (xb) {
        short8v u;
        #pragma unroll
        for (int k = 0; k < 8; ++k) u[k] = (short)f2bf(o[k]);
        *(short8v*)(xb + (size_t)i * 8) = u;
    }
}

// single-tensor variant, optional bf16 out, optional health add (+0.1*s[row])
__global__ void bn_apply1b(const ushort* __restrict__ x, const float* __restrict__ stat,
                           const float* __restrict__ g, const float* __restrict__ b, float invN,
                           float* __restrict__ xo, ushort* __restrict__ xb, int N,
                           const float* __restrict__ health) {
    int i = blockIdx.x * 256 + threadIdx.x;
    if (i >= N * 16) return;
    int c16 = i & 15;
    short8v v = *(const short8v*)(x + (size_t)i * 8);
    float sc[8], sh[8];
    bn_scale_shift(stat, g, b, invN, c16 * 8, sc, sh);
    float hv = health ? 0.1f * health[i >> 4] : 0.f;
    float o[8];
    #pragma unroll
    for (int k = 0; k < 8; ++k) {
        float f = bf2f((ushort)v[k]) * sc[k] + sh[k];
        o[k] = (f > 0.f ? f : __expf(f) - 1.f) + hv;
    }
    if (xo) {
        *(float4*)(xo + (size_t)i * 8)     = make_float4(o[0], o[1], o[2], o[3]);
        *(float4*)(xo + (size_t)i * 8 + 4) = make_float4(o[4], o[5], o[6], o[7]);
    }
    if (xb) {
        short8v u;
        #pragma unroll
        for (int k = 0; k < 8; ++k) u[k] = (short)f2bf(o[k]);
        *(short8v*)(xb + (size_t)i * 8) = u;
    }
}

// ---------------------------------------------------------------------------
// Fused MLP: prefs[u] = tanh( leaky_relu(Xb[u]@hw1 + hb1, 0.01) @ hw2 + hb2 )
// ---------------------------------------------------------------------------
__global__ __launch_bounds__(256) void mlp_mfma(const ushort* __restrict__ Xb,
                                                const ushort* __restrict__ Wt,   // hw1t [64][128]
                                                const float* __restrict__ hb1,
                                                const float* __restrict__ hw2,
                                                const float* __restrict__ hb2,
                                                float* __restrict__ prefs, int N) {
    __shared__ short Xs[128 * LDR];
    __shared__ short Ws[64 * LDR];
    const int t = threadIdx.x;
    const int row0 = blockIdx.x * 128;

    for (int i = t; i < 128 * 16; i += 256) {
        int r = i >> 4, c8 = (i & 15) << 3;
        short8v v = {};
        if (row0 + r < N) v = *(const short8v*)(Xb + (size_t)(row0 + r) * 128 + c8);
        *(short8v*)(&Xs[r * LDR + c8]) = v;
    }
    for (int i = t; i < 64 * 16; i += 256) {
        int r = i >> 4, c8 = (i & 15) << 3;
        *(short8v*)(&Ws[r * LDR + c8]) = *(const short8v*)(Wt + r * 128 + c8);
    }
    __syncthreads();

    const int w = t >> 6, l = t & 63;
    const int m0 = w * 32;
    const int frow = l & 15;
    const int koff = (l >> 4) << 3;

    float4v acc[2][4];
    #pragma unroll
    for (int m = 0; m < 2; ++m)
        #pragma unroll
        for (int n = 0; n < 4; ++n) acc[m][n] = (float4v)0.f;

    #pragma unroll
    for (int ks = 0; ks < 4; ++ks) {
        const int k0 = ks * 32 + koff;
        short8v a[2], b[4];
        #pragma unroll
        for (int m = 0; m < 2; ++m)
            a[m] = *(const short8v*)(&Xs[(m0 + m * 16 + frow) * LDR + k0]);
        #pragma unroll
        for (int n = 0; n < 4; ++n)
            b[n] = *(const short8v*)(&Ws[(n * 16 + frow) * LDR + k0]);
        #pragma unroll
        for (int m = 0; m < 2; ++m)
            #pragma unroll
            for (int n = 0; n < 4; ++n)
                acc[m][n] = __builtin_amdgcn_mfma_f32_16x16x32_bf16(a[m], b[n], acc[m][n], 0, 0, 0);
    }

    float hb1v[4], hw2v[4];
    #pragma unroll
    for (int n = 0; n < 4; ++n) {
        int col = n * 16 + (l & 15);
        hb1v[n] = hb1[col];
        hw2v[n] = hw2[col];
    }
    const float hb2v = hb2[0];
    #pragma unroll
    for (int m = 0; m < 2; ++m) {
        #pragma unroll
        for (int r4 = 0; r4 < 4; ++r4) {
            float p = 0.f;
            #pragma unroll
            for (int n = 0; n < 4; ++n) {
                float v = acc[m][n][r4] + hb1v[n];
                v = v > 0.f ? v : 0.01f * v;
                p += v * hw2v[n];
            }
            p += __shfl_xor(p, 1);
            p += __shfl_xor(p, 2);
            p += __shfl_xor(p, 4);
            p += __shfl_xor(p, 8);
            int grow = row0 + m0 + m * 16 + ((l >> 4) << 2) + r4;
            if ((l & 15) == 0 && grow < N) prefs[grow] = tanhf(p + hb2v);
        }
    }
}

// s[he_food[e]] += prefs[he_user[e]] * score[e]
__global__ void health_scatter(const int* __restrict__ hu, const int* __restrict__ hf,
                               const float* __restrict__ score, const float* __restrict__ prefs,
                               float* __restrict__ s, int E) {
    int e = blockIdx.x * 256 + threadIdx.x;
    if (e >= E) return;
    atomicAdd(&s[hf[e]], prefs[hu[e]] * score[e]);
}

// ---------------------------------------------------------------------------
extern "C" void kernel_launch(void* const* d_in, const int* in_sizes, int n_in,
                              void* d_out, int out_size, void* d_ws, size_t ws_size,
                              hipStream_t stream) {
    const float* x_user = (const float*)d_in[0];
    const float* x_food = (const float*)d_in[1];
    const int* uf_src = (const int*)d_in[2];
    const int* uf_dst = (const int*)d_in[3];
    const int* fu_src = (const int*)d_in[4];
    const int* fu_dst = (const int*)d_in[5];
    const int* he_user = (const int*)d_in[6];
    const int* he_food = (const int*)d_in[7];
    const float* scores = (const float*)d_in[8];
    // GAT biases (d_in[13],[18],[23],[28]) cancel through BatchNorm — unused.
    const float* bn1_user_g = (const float*)d_in[29];
    const float* bn1_user_b = (const float*)d_in[30];
    const float* bn1_food_g = (const float*)d_in[31];
    const float* bn1_food_b = (const float*)d_in[32];
    const float* bn2_user_g = (const float*)d_in[33];
    const float* bn2_user_b = (const float*)d_in[34];
    const float* bn2_food_g = (const float*)d_in[35];
    const float* bn2_food_b = (const float*)d_in[36];
    const float* hw1 = (const float*)d_in[37];
    const float* hb1 = (const float*)d_in[38];
    const float* hw2 = (const float*)d_in[39];
    const float* hb2 = (const float*)d_in[40];

    float* outp  = (float*)d_out;
    float* xu2   = outp;                          // [NU,128]
    float* xf2   = outp + (size_t)NU_ * 128;      // [NF,128]
    float* prefs = xf2 + (size_t)NF_ * 128;       // [NU]

    // ---- workspace layout ----
    float* ws = (float*)d_ws;
    ushort* hs_u = (ushort*)ws;                        // NU*128 bf16
    ushort* hs_f = hs_u + (size_t)NU_ * 128;           // NF*128
    float* base1 = ws + (size_t)(NU_ + NF_) * 64;
    ushort* xu1b = (ushort*)base1;                     // NU*128
    ushort* xf1b = xu1b + (size_t)NU_ * 128;           // NF*128
    float* base2 = base1 + (size_t)(NU_ + NF_) * 64;
    ushort* xu2b = (ushort*)base2;                     // NU*128 (input bf16, then L2 raw out)
    ushort* xf2b = xu2b + (size_t)NU_ * 128;           // NF*128
    float* base3 = base2 + (size_t)(NU_ + NF_) * 64;
    float* asn_u = base3;                              // NU
    float* adn_u = asn_u + NU_;                        // NU
    float* asn_f = adn_u + NU_;                        // NF
    float* adn_f = asn_f + NF_;                        // NF
    // --- zeroed-once region ---
    float* stat4 = adn_f + NF_;                        // 4*256
    float* sbuf  = stat4 + 1024;                       // NF
    int*   deg_f = (int*)(sbuf + NF_);                 // NF
    int*   deg_u = deg_f + NF_;                        // NU
    // --- zeroed-once region end ---
    ushort* buck_f = (ushort*)(deg_u + NU_);           // NF*CAPF ushort
    ushort* buck_u = buck_f + (size_t)NF_ * CAPF_;     // NU*CAPU ushort
    ushort* wt0  = buck_u + (size_t)NU_ * CAPU_;       // 128*128 each
    ushort* wt1  = wt0 + 16384;
    ushort* wt2  = wt1 + 16384;
    ushort* wt3  = wt2 + 16384;
    ushort* hw1t = wt3 + 16384;                        // 64*128
    float* vall  = (float*)(hw1t + 8192);              // 8*128

    const size_t zero_elems = 1024 + NF_ + NF_ + NU_;
    hipMemsetAsync(stat4, 0, zero_elems * sizeof(float), stream);

    // --- fused preprocessing: XCD-partitioned fill first, BW sections backfill ---
    const int EB = (E_ + 255) / 256;
    const int FBLK = 8 * EB;
    PPArgs pp;
    pp.uf_src = uf_src; pp.uf_dst = uf_dst;
    pp.fu_src = fu_src; pp.fu_dst = fu_dst;
    pp.deg_f = deg_f; pp.deg_u = deg_u;
    pp.buck_f = buck_f; pp.buck_u = buck_u;
    pp.xu = x_user; pp.xf = x_food; pp.bu = xu2b; pp.bfo = xf2b;
    pp.W[0] = (const float*)d_in[9];  pp.T[0] = wt0;
    pp.W[1] = (const float*)d_in[14]; pp.T[1] = wt1;
    pp.W[2] = (const float*)d_in[19]; pp.T[2] = wt2;
    pp.W[3] = (const float*)d_in[24]; pp.T[3] = wt3;
    pp.W[4] = hw1;                    pp.T[4] = hw1t;
    pp.waW[0] = (const float*)d_in[9];  pp.waA[0] = (const float*)d_in[11];
    pp.waW[1] = (const float*)d_in[10]; pp.waA[1] = (const float*)d_in[12];
    pp.waW[2] = (const float*)d_in[14]; pp.waA[2] = (const float*)d_in[16];
    pp.waW[3] = (const float*)d_in[15]; pp.waA[3] = (const float*)d_in[17];
    pp.waW[4] = (const float*)d_in[19]; pp.waA[4] = (const float*)d_in[21];
    pp.waW[5] = (const float*)d_in[20]; pp.waA[5] = (const float*)d_in[22];
    pp.waW[6] = (const float*)d_in[24]; pp.waA[6] = (const float*)d_in[26];
    pp.waW[7] = (const float*)d_in[25]; pp.waA[7] = (const float*)d_in[27];
    pp.vall = vall;
    const int PPB = 2 * FBLK + NU_ * 32 / 256 + NF_ * 32 / 256 + 288 + 256;
    preprocess<<<PPB, 256, 0, stream>>>(pp);

    const int GB  = (NU_ + 127) / 128 + (NF_ + 127) / 128;        // 587
    const int MVB = (NU_ + NF_ + 3) / 4;                          // 18750
    const int AGB = (NF_ + 3) / 4 + (NU_ + 3) / 4;                // 18750
    const int APB = ((NU_ + NF_) * 16 + 255) / 256;               // 4688
    const float invNU = 1.0f / NU_, invNF = 1.0f / NF_;

    // ---- layer 1 ----
    gemm_both<<<GB, 256, 0, stream>>>(xu2b, wt0, hs_u, xf2b, wt1, hs_f);
    matvec4<<<MVB, 256, 0, stream>>>(xu2b, xf2b, vall + 0, vall + 384, vall + 128, vall + 256,
                                     asn_u, adn_u, adn_f, asn_f);
    gat_agg_both<<<AGB, 256, 0, stream>>>(deg_f, buck_f, asn_u, adn_f, hs_u, xf1b,
                                          deg_u, buck_u, asn_f, adn_u, hs_f, xu1b);
    bn_stats2b<<<768, 256, 0, stream>>>(xu1b, stat4 + 0, NU_, 512, xf1b, stat4 + 256, NF_, 256);
    bn_apply2b<<<APB, 256, 0, stream>>>(
        xu1b, stat4 + 0,   bn1_user_g, bn1_user_b, invNU, (float*)nullptr, xu1b, NU_,
        xf1b, stat4 + 256, bn1_food_g, bn1_food_b, invNF, (float*)nullptr, xf1b, NF_);

    // ---- layer 2 ----
    gemm_both<<<GB, 256, 0, stream>>>(xu1b, wt2, hs_u, xf1b, wt3, hs_f);
    matvec4<<<MVB, 256, 0, stream>>>(xu1b, xf1b, vall + 512, vall + 896, vall + 640, vall + 768,
                                     asn_u, adn_u, adn_f, asn_f);
    gat_agg_both<<<AGB, 256, 0, stream>>>(deg_f, buck_f, asn_u, adn_f, hs_u, xf2b,
                                          deg_u, buck_u, asn_f, adn_u, hs_f, xu2b);
    bn_stats2b<<<768, 256, 0, stream>>>(xu2b, stat4 + 512, NU_, 512, xf2b, stat4 + 768, NF_, 256);
    // user half: fp32 out + bf16 (for MLP)
    bn_apply1b<<<(NU_ * 16 + 255) / 256, 256, 0, stream>>>(
        xu2b, stat4 + 512, bn2_user_g, bn2_user_b, invNU, xu2, xu2b, NU_, (const float*)nullptr);
    // ---- health preference MLP + scatter ----
    mlp_mfma<<<(NU_ + 127) / 128, 256, 0, stream>>>(xu2b, hw1t, hb1, hw2, hb2, prefs, NU_);
    health_scatter<<<EB, 256, 0, stream>>>(he_user, he_food, scores, prefs, sbuf, E_);
    // food half: fp32 out with fused health add
    bn_apply1b<<<(NF_ * 16 + 255) / 256, 256, 0, stream>>>(
        xf2b, stat4 + 768, bn2_food_g, bn2_food_b, invNF, xf2, (ushort*)nullptr, NF_, sbuf);
}